// Round 12
// baseline (226.710 us; speedup 1.0000x reference)
//
#include <hip/hip_runtime.h>
#include <math.h>

// Round 24: flash = R14's KV-split 2-wave structure with the spill cause
// removed. R23 confirmed the intensity law (halving q-rows/wave halved
// MFMA:load ratio -> 67us) and that (128,3) imposes no reg cap (52 regs,
// zero spill). R14's T-split halves loads AND MFMAs together (ratio
// preserved), 24 waves/CU; its failure was only the (128,5)~51-reg cap.
// Now: R14 body + (128,3) + XCD swizzle + frag-linear attnb store.
// Additive fixed-max partials combined via one LDS exchange at the end.
// GEMMs/cast byte-identical to R22 (180.2us best).

typedef __bf16 bf16x8 __attribute__((ext_vector_type(8)));
typedef float  f32x4  __attribute__((ext_vector_type(4)));
typedef unsigned u32x2 __attribute__((ext_vector_type(2)));
typedef unsigned u32x4 __attribute__((ext_vector_type(4)));
typedef unsigned short ushort_t;

__device__ __forceinline__ unsigned short f2bf(float f) {
    unsigned u = __float_as_uint(f);
    u += 0x7fffu + ((u >> 16) & 1u);          // round-to-nearest-even
    return (unsigned short)(u >> 16);
}
__device__ __forceinline__ unsigned pk16(unsigned short lo, unsigned short hi) {
    return (unsigned)lo | ((unsigned)hi << 16);
}

// ---------------------------------------------------------------------------
// cast (1D grid, 4224 blocks, 4 tiles/block): everything frag-linear.
// Tile (t,kb) of source S holds S[t*16+c][kb*32+g*8..+7] at
// ((t*24+kb)*64 + L)*8. Tiles 0..12287 = x->xb; then 4x1152 for weights.
// ---------------------------------------------------------------------------
__global__ __launch_bounds__(256)
void cast_all(const float* __restrict__ x,
              const float* __restrict__ w0, const float* __restrict__ w1,
              const float* __restrict__ w2, const float* __restrict__ w3,
              ushort_t* __restrict__ xb, ushort_t* __restrict__ wb0,
              ushort_t* __restrict__ wb1, ushort_t* __restrict__ wb2,
              ushort_t* __restrict__ wb3)
{
    const int wt0 = blockIdx.x * 4 + (threadIdx.x >> 6);
    const int L = threadIdx.x & 63, c = L & 15, g = L >> 4;
    const float* s; ushort_t* d; int tile;
    if (wt0 < 12288) {                 // x: 512 t-tiles x 24 kb
        s = x; d = xb; tile = wt0;
    } else {
        const int wt = wt0 - 12288;    // weights: 48 t-tiles x 24 kb each
        const int wsel = wt / 1152; tile = wt % 1152;
        switch (wsel) {
            case 0:  s = w0; d = wb0; break;
            case 1:  s = w1; d = wb1; break;
            case 2:  s = w2; d = wb2; break;
            default: s = w3; d = wb3; break;
        }
    }
    const int t = tile / 24, kb = tile % 24;
    const float* sp = s + (size_t)(t * 16 + c) * 768 + kb * 32 + g * 8;
    const float4 f0 = *(const float4*)sp;
    const float4 f1 = *(const float4*)(sp + 4);
    ushort4 p0, p1;
    p0.x = f2bf(f0.x); p0.y = f2bf(f0.y); p0.z = f2bf(f0.z); p0.w = f2bf(f0.w);
    p1.x = f2bf(f1.x); p1.y = f2bf(f1.y); p1.z = f2bf(f1.z); p1.w = f2bf(f1.w);
    ushort_t* dp = d + ((size_t)tile * 64 + L) * 8;
    *(ushort4*)dp       = p0;
    *(ushort4*)(dp + 4) = p1;
}

// ---------------------------------------------------------------------------
// Z-fused QKV GEMM, barrier-free (R20 shape): 64m x 128n block, 4 waves
// (each 64m x 32n x 3z). A and W frags direct from frag-linear global
// with in-place prefetch. 1D grid 768, XCD-chunked: xcd owns a by-range.
// ---------------------------------------------------------------------------
__global__ __launch_bounds__(256, 3)
void gemm_qkv(const ushort_t* __restrict__ xb,
              const ushort_t* __restrict__ wqb, const ushort_t* __restrict__ wkb,
              const ushort_t* __restrict__ wvb,
              const float* __restrict__ bq, const float* __restrict__ bk,
              const float* __restrict__ bv,
              ushort_t* __restrict__ Qh, ushort_t* __restrict__ Kl,
              ushort_t* __restrict__ Vl)
{
    __shared__ ushort_t smem[9216];      // epilogue scratch 4x2304, per-wave
    const int tid = threadIdx.x, L = tid & 63, wv = tid >> 6;
    const int c = L & 15, g = L >> 4;
    // XCD A-locality: xcd = bid&7 handles by in [xcd*16, xcd*16+16), all bx.
    const int bid = blockIdx.x;
    const int xcd = bid & 7, idx = bid >> 3;       // idx 0..95
    const int by = xcd * 16 + idx / 6, bx = idx % 6;
    const int n0 = bx * 128, m0 = by * 64;

    // A frag tiles t = by*4 + i; af[i] at ap + i*12288 + kb*512
    const ushort_t* ap = xb + (size_t)(by * 4) * 24 * 512 + (size_t)L * 8;
    // W frag tiles t = bx*8 + wv*2 + j
    const size_t wbase = ((size_t)(bx * 8 + wv * 2) * 24 * 64 + L) * 8;
    const ushort_t* wqp = wqb + wbase;
    const ushort_t* wkp = wkb + wbase;
    const ushort_t* wvp = wvb + wbase;
    // j/i tile stride = 24*64*8 = 12288 shorts; kb stride = 512 shorts

    f32x4 acc[3][4][2];
#pragma unroll
    for (int z = 0; z < 3; ++z)
#pragma unroll
        for (int i = 0; i < 4; ++i)
#pragma unroll
            for (int j = 0; j < 2; ++j) acc[z][i][j] = (f32x4){0.f, 0.f, 0.f, 0.f};

    bf16x8 af[4], wf[3][2];
#pragma unroll
    for (int i = 0; i < 4; ++i) af[i] = *(const bf16x8*)(ap + i * 12288);
#pragma unroll
    for (int j = 0; j < 2; ++j) {
        wf[0][j] = *(const bf16x8*)(wqp + j * 12288);
        wf[1][j] = *(const bf16x8*)(wkp + j * 12288);
        wf[2][j] = *(const bf16x8*)(wvp + j * 12288);
    }

    for (int kb = 0; kb < 24; ++kb) {
#pragma unroll
        for (int z = 0; z < 3; ++z)
#pragma unroll
            for (int i = 0; i < 4; ++i)
#pragma unroll
                for (int j = 0; j < 2; ++j)
                    acc[z][i][j] = __builtin_amdgcn_mfma_f32_16x16x32_bf16(
                        af[i], wf[z][j], acc[z][i][j], 0, 0, 0);
        const int kn = (kb < 23) ? kb + 1 : 23;
#pragma unroll
        for (int i = 0; i < 4; ++i)
            af[i] = *(const bf16x8*)(ap + i * 12288 + kn * 512);
#pragma unroll
        for (int j = 0; j < 2; ++j) {
            wf[0][j] = *(const bf16x8*)(wqp + j * 12288 + kn * 512);
            wf[1][j] = *(const bf16x8*)(wkp + j * 12288 + kn * 512);
            wf[2][j] = *(const bf16x8*)(wvp + j * 12288 + kn * 512);
        }
    }

    // ---------------- epilogues (per-wave private strips, no syncs) -------
    const int b  = m0 >> 10, nb = m0 & 1023;
    const int hcol = n0 + wv * 32;
    const int h = hcol >> 6, uh = (hcol >> 5) & 1;
    const int bh = b * 12 + h;
    ushort_t* scr = smem + wv * 2304;

    float bias2[3][2];
#pragma unroll
    for (int j = 0; j < 2; ++j) {
        bias2[0][j] = bq[hcol + j * 16 + c];
        bias2[1][j] = bk[hcol + j * 16 + c];
        bias2[2][j] = bv[hcol + j * 16 + c];
    }

    // z=0: Q plain [bh][token][hd64]; token-major strip [64][36]
#pragma unroll
    for (int i = 0; i < 4; ++i)
#pragma unroll
        for (int j = 0; j < 2; ++j)
#pragma unroll
            for (int r = 0; r < 4; ++r)
                scr[(i * 16 + g * 4 + r) * 36 + j * 16 + c] =
                    f2bf(acc[0][i][j][r] + bias2[0][j]);
#pragma unroll
    for (int e = 0; e < 4; ++e) {
        const int slot = e * 64 + L;
        const int row = slot >> 2, ch = slot & 3;
        const u32x4 v = *(const u32x4*)&scr[row * 36 + ch * 8];
        *(u32x4*)&Qh[((size_t)bh * 1024 + nb + row) * 64 + uh * 32 + ch * 8] = v;
    }

    // z=1: K frag-linear; token-major strip again
#pragma unroll
    for (int i = 0; i < 4; ++i)
#pragma unroll
        for (int j = 0; j < 2; ++j)
#pragma unroll
            for (int r = 0; r < 4; ++r)
                scr[(i * 16 + g * 4 + r) * 36 + j * 16 + c] =
                    f2bf(acc[1][i][j][r] + bias2[1][j]);
#pragma unroll
    for (int tau = 0; tau < 4; ++tau) {
        const u32x4 v = *(const u32x4*)&scr[(tau * 16 + c) * 36 + g * 8];
        *(u32x4*)&Kl[(((size_t)bh * 64 + (nb >> 4) + tau) * 2 + uh) * 512
                     + (size_t)L * 8] = v;
    }

    // z=2: V frag-linear; hd-major strip [32][68]
#pragma unroll
    for (int i = 0; i < 4; ++i)
#pragma unroll
        for (int j = 0; j < 2; ++j)
#pragma unroll
            for (int r = 0; r < 4; ++r)
                scr[(j * 16 + c) * 68 + i * 16 + g * 4 + r] =
                    f2bf(acc[2][i][j][r] + bias2[2][j]);
    const int T = nb >> 6;
#pragma unroll
    for (int t = 0; t < 4; ++t) {
        const int htl = t >> 1, u = t & 1;
        const u32x4 v = *(const u32x4*)&scr[(htl * 16 + c) * 68 + u * 32 + g * 8];
        *(u32x4*)&Vl[((((size_t)bh * 4 + uh * 2 + htl) * 16 + T) * 2 + u) * 512
                     + (size_t)L * 8] = v;
    }
}

// ---------------------------------------------------------------------------
// Out-proj GEMM, LDS-free/barrier-free (R20 shape): 64m x 128n block,
// 4 waves. 1D grid 768, XCD-chunked like qkv.
// ---------------------------------------------------------------------------
__global__ __launch_bounds__(256, 3)
void gemm_outp(const ushort_t* __restrict__ attnb, const ushort_t* __restrict__ wob,
               const float* __restrict__ bo, float* __restrict__ out)
{
    const int tid = threadIdx.x, L = tid & 63, wv = tid >> 6;
    const int c = L & 15, g = L >> 4;
    const int bid = blockIdx.x;
    const int xcd = bid & 7, idx = bid >> 3;
    const int by = xcd * 16 + idx / 6, bx = idx % 6;
    const int n0 = bx * 128, m0 = by * 64;

    const ushort_t* ap = attnb + (size_t)(by * 4) * 24 * 512 + (size_t)L * 8;
    const size_t wbase = ((size_t)(bx * 8 + wv * 2) * 24 * 64 + L) * 8;
    const ushort_t* wop = wob + wbase;

    f32x4 acc[4][2];
#pragma unroll
    for (int i = 0; i < 4; ++i)
#pragma unroll
        for (int j = 0; j < 2; ++j) acc[i][j] = (f32x4){0.f, 0.f, 0.f, 0.f};

    bf16x8 af[4], wf[2];
#pragma unroll
    for (int i = 0; i < 4; ++i) af[i] = *(const bf16x8*)(ap + i * 12288);
#pragma unroll
    for (int j = 0; j < 2; ++j) wf[j] = *(const bf16x8*)(wop + j * 12288);

    for (int kb = 0; kb < 24; ++kb) {
#pragma unroll
        for (int i = 0; i < 4; ++i)
#pragma unroll
            for (int j = 0; j < 2; ++j)
                acc[i][j] = __builtin_amdgcn_mfma_f32_16x16x32_bf16(
                    af[i], wf[j], acc[i][j], 0, 0, 0);
        const int kn = (kb < 23) ? kb + 1 : 23;
#pragma unroll
        for (int i = 0; i < 4; ++i)
            af[i] = *(const bf16x8*)(ap + i * 12288 + kn * 512);
#pragma unroll
        for (int j = 0; j < 2; ++j)
            wf[j] = *(const bf16x8*)(wop + j * 12288 + kn * 512);
    }

#pragma unroll
    for (int i = 0; i < 4; ++i) {
        const int row = m0 + i * 16 + g * 4;
#pragma unroll
        for (int j = 0; j < 2; ++j) {
            const int col = n0 + wv * 32 + j * 16 + c;
            const float bsvo = bo[col];
#pragma unroll
            for (int r = 0; r < 4; ++r)
                out[(size_t)(row + r) * 768 + col] = acc[i][j][r] + bsvo;
        }
    }
}

// ---------------------------------------------------------------------------
// Flash (R24): 2-wave KV-split. Wave w computes ALL 32 q-rows over its
// T in [8w,8w+8) -- loads and MFMAs halve together (intensity law,
// R21/R23). Fixed-max partials are additive -> one LDS combine at the
// end (2 barriers total, none in loop). launch_bounds(128,3): no reg
// cap (R23: natural allocation, zero spill). XCD swizzle + frag-linear
// attnb store kept. Tripwires: VGPR>=120 or WRITE>12288 -> spills.
// ---------------------------------------------------------------------------
__global__ __launch_bounds__(128, 3)
void flash_bf16(const ushort_t* __restrict__ Q, const ushort_t* __restrict__ Kl,
                const ushort_t* __restrict__ Vl, ushort_t* __restrict__ attnb)
{
    // [0,4352) shorts: main-loop P-strips (w*2+u)*1088; combine aliases:
    //   oF float[2][1024] at 0..4096 shorts, lsF float[2][64] at 4096..4352.
    // [4352,6528) shorts: store strips, w*1088.
    __shared__ ushort_t smem[6528];
    const int tid = threadIdx.x;
    const int L = tid & 63, w = tid >> 6;      // lane, wave(=T-half)
    const int c = L & 15, g = L >> 4;
    const int bid = blockIdx.x;
    const int slot = bid >> 3;                 // 0..383 within XCD
    const int bh = (bid & 7) * 12 + (slot >> 5);
    const int q0 = (slot & 31) * 32;
    const float SC2 = 0.05205954985329743f;    // 768^-0.5 * log2(e)

    const ushort_t* Qp = Q + ((size_t)bh * 1024 + q0 + c) * 64 + g * 8;
    bf16x8 qf[2][2];
    qf[0][0] = *(const bf16x8*)Qp;
    qf[0][1] = *(const bf16x8*)(Qp + 32);
    qf[1][0] = *(const bf16x8*)(Qp + 16 * 64);
    qf[1][1] = *(const bf16x8*)(Qp + 16 * 64 + 32);

    const ushort_t* Kb = Kl + (size_t)bh * 65536 + (size_t)L * 8;
    const ushort_t* Vb = Vl + (size_t)bh * 65536 + (size_t)L * 8;

    ushort_t* st0 = smem + (w * 2 + 0) * 1088;
    ushort_t* st1 = smem + (w * 2 + 1) * 1088;

    f32x4 o[2][4];
#pragma unroll
    for (int u = 0; u < 2; ++u)
#pragma unroll
        for (int ht = 0; ht < 4; ++ht) o[u][ht] = (f32x4){0.f, 0.f, 0.f, 0.f};
    float ls[2] = {0.f, 0.f};

    const int Tbeg = w * 8;
    bf16x8 kf0[4], kf1[4];
#pragma unroll
    for (int ct = 0; ct < 4; ++ct) {
        const ushort_t* kp = Kb + (size_t)((Tbeg * 4 + ct) * 2) * 512;
        kf0[ct] = *(const bf16x8*)kp;
        kf1[ct] = *(const bf16x8*)(kp + 512);
    }

#pragma unroll 2
    for (int T = Tbeg; T < Tbeg + 8; ++T) {
        bf16x8 vf0[4], vf1[4];
#pragma unroll
        for (int ht = 0; ht < 4; ++ht) {
            const ushort_t* vp = Vb + (size_t)((ht * 16 + T) * 2) * 512;
            vf0[ht] = *(const bf16x8*)vp;
            vf1[ht] = *(const bf16x8*)(vp + 512);
        }
        f32x4 s[2][4];
#pragma unroll
        for (int u = 0; u < 2; ++u)
#pragma unroll
            for (int ct = 0; ct < 4; ++ct) {
                f32x4 zz = (f32x4){0.f, 0.f, 0.f, 0.f};
                zz = __builtin_amdgcn_mfma_f32_16x16x32_bf16(kf0[ct], qf[u][0], zz, 0, 0, 0);
                zz = __builtin_amdgcn_mfma_f32_16x16x32_bf16(kf1[ct], qf[u][1], zz, 0, 0, 0);
                s[u][ct] = zz;
            }
        const int Tn = (T < Tbeg + 7) ? T + 1 : T;
#pragma unroll
        for (int ct = 0; ct < 4; ++ct) {
            const ushort_t* kp = Kb + (size_t)((Tn * 4 + ct) * 2) * 512;
            kf0[ct] = *(const bf16x8*)kp;
            kf1[ct] = *(const bf16x8*)(kp + 512);
        }
#pragma unroll
        for (int u = 0; u < 2; ++u) {
            ushort_t* st = u ? st1 : st0;
#pragma unroll
            for (int ct = 0; ct < 4; ++ct) {
                float pv[4];
#pragma unroll
                for (int r = 0; r < 4; ++r)
                    pv[r] = __builtin_amdgcn_exp2f(s[u][ct][r] * SC2);
                ls[u] += (pv[0] + pv[1]) + (pv[2] + pv[3]);
                const unsigned w01 = __builtin_amdgcn_perm(
                    __float_as_uint(pv[1]), __float_as_uint(pv[0]), 0x07060302u);
                const unsigned w23 = __builtin_amdgcn_perm(
                    __float_as_uint(pv[3]), __float_as_uint(pv[2]), 0x07060302u);
                *(u32x2*)&st[c * 68 + ct * 16 + g * 4] = (u32x2){w01, w23};
            }
        }
#pragma unroll
        for (int u = 0; u < 2; ++u) {
            const ushort_t* st = u ? st1 : st0;
            const int pb = c * 68 + g * 8;
            const u32x4 pa  = *(const u32x4*)&st[pb];
            const u32x4 pbv = *(const u32x4*)&st[pb + 32];
            const bf16x8 pf0 = __builtin_bit_cast(bf16x8, pa);
            const bf16x8 pf1 = __builtin_bit_cast(bf16x8, pbv);
#pragma unroll
            for (int ht = 0; ht < 4; ++ht) {
                o[u][ht] = __builtin_amdgcn_mfma_f32_16x16x32_bf16(vf0[ht], pf0, o[u][ht], 0, 0, 0);
                o[u][ht] = __builtin_amdgcn_mfma_f32_16x16x32_bf16(vf1[ht], pf1, o[u][ht], 0, 0, 0);
            }
        }
    }

    // ---------------- cross-wave combine (additive partials) ----------------
    const int b = bh / 12, h = bh % 12;
    float* oF  = (float*)smem;          // [srcwave][ht*4+r][lane]
    float* lsF = oF + 2048;             // [srcwave][lane]
    const int uo = 1 - w;               // qgroup this wave does NOT output

    __syncthreads();                    // main-loop strip reads all done
#pragma unroll
    for (int ht = 0; ht < 4; ++ht)
#pragma unroll
        for (int r = 0; r < 4; ++r)
            oF[w * 1024 + (ht * 4 + r) * 64 + L] = o[uo][ht][r];
    lsF[w * 64 + L] = ls[uo];
    __syncthreads();                    // peer partials visible

    float l = ls[w] + lsF[uo * 64 + L];
    l += __shfl_xor(l, 16);
    l += __shfl_xor(l, 32);
    const float inv = 1.f / l;

    ushort_t* strip = smem + 4352 + w * 1088;
#pragma unroll
    for (int ht = 0; ht < 4; ++ht) {
        const float v0 = o[w][ht][0] + oF[uo * 1024 + (ht * 4 + 0) * 64 + L];
        const float v1 = o[w][ht][1] + oF[uo * 1024 + (ht * 4 + 1) * 64 + L];
        const float v2 = o[w][ht][2] + oF[uo * 1024 + (ht * 4 + 2) * 64 + L];
        const float v3 = o[w][ht][3] + oF[uo * 1024 + (ht * 4 + 3) * 64 + L];
        const unsigned w0 = pk16(f2bf(v0 * inv), f2bf(v1 * inv));
        const unsigned w1 = pk16(f2bf(v2 * inv), f2bf(v3 * inv));
        *(u32x2*)&strip[c * 68 + ht * 16 + g * 4] = (u32x2){w0, w1};
    }
    // frag-linear store: wave w outputs qgroup w -> tile tB + w, kb =
    // h*2 + kbi; lane L holds row c, hd kbi*32 + g*8..+7.
    const int tB = b * 64 + (q0 >> 4);
#pragma unroll
    for (int kbi = 0; kbi < 2; ++kbi) {
        const u32x4 v = *(const u32x4*)&strip[c * 68 + kbi * 32 + g * 8];
        *(u32x4*)&attnb[(((size_t)(tB + w) * 24 + h * 2 + kbi) * 64 + L) * 8] = v;
    }
}

extern "C" void kernel_launch(void* const* d_in, const int* in_sizes, int n_in,
                              void* d_out, int out_size, void* d_ws, size_t ws_size,
                              hipStream_t stream)
{
    const float* x  = (const float*)d_in[0];
    const float* Wq = (const float*)d_in[1];
    const float* bq = (const float*)d_in[2];
    const float* Wk = (const float*)d_in[3];
    const float* bk = (const float*)d_in[4];
    const float* Wv = (const float*)d_in[5];
    const float* bv = (const float*)d_in[6];
    const float* Wo = (const float*)d_in[7];
    const float* bo = (const float*)d_in[8];
    float* out = (float*)d_out;

    char* ws = (char*)d_ws;
    ushort_t* xb    = (ushort_t*)(ws);
    ushort_t* wqb   = (ushort_t*)(ws + 12582912);
    ushort_t* wkb   = (ushort_t*)(ws + 12582912 + 1179648);
    ushort_t* wvb   = (ushort_t*)(ws + 12582912 + 2359296);
    ushort_t* wob   = (ushort_t*)(ws + 12582912 + 3538944);
    ushort_t* Qh    = (ushort_t*)(ws + 17301504);
    ushort_t* Kl    = (ushort_t*)(ws + 29884416);
    ushort_t* Vl    = (ushort_t*)(ws + 42467328);
    ushort_t* attnb = (ushort_t*)(ws + 55050240);

    cast_all<<<dim3(4224), 256, 0, stream>>>(x, Wq, Wk, Wv, Wo,
                                             xb, wqb, wkb, wvb, wob);
    gemm_qkv<<<dim3(768), 256, 0, stream>>>(xb, wqb, wkb, wvb,
                                            bq, bk, bv, Qh, Kl, Vl);
    flash_bf16<<<dim3(3072), 128, 0, stream>>>(Qh, Kl, Vl, attnb);
    gemm_outp<<<dim3(768), 256, 0, stream>>>(attnb, wob, bo, out);
}

// Round 13
// 181.060 us; speedup vs baseline: 1.2521x; 1.2521x over previous
//
#include <hip/hip_runtime.h>
#include <math.h>

// Round 25: exact revert to R22 (180.2us session best). R24 closed the
// flash multi-wave ledger: full-state 2-wave variants spill (~180 live
// regs vs 170 cap -> 82MB scratch WRITE; R14's 102 cap -> 639MB), and
// halved-state variants lose MFMA:load intensity (R23: 67us). The
// 1-wave 84-reg body at 3 waves/SIMD is the unique feasible point of
// the register/intensity/occupancy triangle. GEMMs: barrier-free
// frag-linear loops + XCD A-chunking (R20+R22). Do not: tighten flash
// launch bounds, add setprio, or re-split flash waves.

typedef __bf16 bf16x8 __attribute__((ext_vector_type(8)));
typedef float  f32x4  __attribute__((ext_vector_type(4)));
typedef unsigned u32x2 __attribute__((ext_vector_type(2)));
typedef unsigned u32x4 __attribute__((ext_vector_type(4)));
typedef unsigned short ushort_t;

__device__ __forceinline__ unsigned short f2bf(float f) {
    unsigned u = __float_as_uint(f);
    u += 0x7fffu + ((u >> 16) & 1u);          // round-to-nearest-even
    return (unsigned short)(u >> 16);
}
__device__ __forceinline__ unsigned pk16(unsigned short lo, unsigned short hi) {
    return (unsigned)lo | ((unsigned)hi << 16);
}

// ---------------------------------------------------------------------------
// cast (1D grid, 4224 blocks, 4 tiles/block): everything frag-linear.
// Tile (t,kb) of source S holds S[t*16+c][kb*32+g*8..+7] at
// ((t*24+kb)*64 + L)*8. Tiles 0..12287 = x->xb; then 4x1152 for weights.
// ---------------------------------------------------------------------------
__global__ __launch_bounds__(256)
void cast_all(const float* __restrict__ x,
              const float* __restrict__ w0, const float* __restrict__ w1,
              const float* __restrict__ w2, const float* __restrict__ w3,
              ushort_t* __restrict__ xb, ushort_t* __restrict__ wb0,
              ushort_t* __restrict__ wb1, ushort_t* __restrict__ wb2,
              ushort_t* __restrict__ wb3)
{
    const int wt0 = blockIdx.x * 4 + (threadIdx.x >> 6);
    const int L = threadIdx.x & 63, c = L & 15, g = L >> 4;
    const float* s; ushort_t* d; int tile;
    if (wt0 < 12288) {                 // x: 512 t-tiles x 24 kb
        s = x; d = xb; tile = wt0;
    } else {
        const int wt = wt0 - 12288;    // weights: 48 t-tiles x 24 kb each
        const int wsel = wt / 1152; tile = wt % 1152;
        switch (wsel) {
            case 0:  s = w0; d = wb0; break;
            case 1:  s = w1; d = wb1; break;
            case 2:  s = w2; d = wb2; break;
            default: s = w3; d = wb3; break;
        }
    }
    const int t = tile / 24, kb = tile % 24;
    const float* sp = s + (size_t)(t * 16 + c) * 768 + kb * 32 + g * 8;
    const float4 f0 = *(const float4*)sp;
    const float4 f1 = *(const float4*)(sp + 4);
    ushort4 p0, p1;
    p0.x = f2bf(f0.x); p0.y = f2bf(f0.y); p0.z = f2bf(f0.z); p0.w = f2bf(f0.w);
    p1.x = f2bf(f1.x); p1.y = f2bf(f1.y); p1.z = f2bf(f1.z); p1.w = f2bf(f1.w);
    ushort_t* dp = d + ((size_t)tile * 64 + L) * 8;
    *(ushort4*)dp       = p0;
    *(ushort4*)(dp + 4) = p1;
}

// ---------------------------------------------------------------------------
// Z-fused QKV GEMM, barrier-free (R20 shape): 64m x 128n block, 4 waves
// (each 64m x 32n x 3z). A and W frags direct from frag-linear global
// with in-place prefetch. 1D grid 768, XCD-chunked: xcd owns a by-range.
// ---------------------------------------------------------------------------
__global__ __launch_bounds__(256, 3)
void gemm_qkv(const ushort_t* __restrict__ xb,
              const ushort_t* __restrict__ wqb, const ushort_t* __restrict__ wkb,
              const ushort_t* __restrict__ wvb,
              const float* __restrict__ bq, const float* __restrict__ bk,
              const float* __restrict__ bv,
              ushort_t* __restrict__ Qh, ushort_t* __restrict__ Kl,
              ushort_t* __restrict__ Vl)
{
    __shared__ ushort_t smem[9216];      // epilogue scratch 4x2304, per-wave
    const int tid = threadIdx.x, L = tid & 63, wv = tid >> 6;
    const int c = L & 15, g = L >> 4;
    // XCD A-locality: xcd = bid&7 handles by in [xcd*16, xcd*16+16), all bx.
    const int bid = blockIdx.x;
    const int xcd = bid & 7, idx = bid >> 3;       // idx 0..95
    const int by = xcd * 16 + idx / 6, bx = idx % 6;
    const int n0 = bx * 128, m0 = by * 64;

    // A frag tiles t = by*4 + i; af[i] at ap + i*12288 + kb*512
    const ushort_t* ap = xb + (size_t)(by * 4) * 24 * 512 + (size_t)L * 8;
    // W frag tiles t = bx*8 + wv*2 + j
    const size_t wbase = ((size_t)(bx * 8 + wv * 2) * 24 * 64 + L) * 8;
    const ushort_t* wqp = wqb + wbase;
    const ushort_t* wkp = wkb + wbase;
    const ushort_t* wvp = wvb + wbase;
    // j/i tile stride = 24*64*8 = 12288 shorts; kb stride = 512 shorts

    f32x4 acc[3][4][2];
#pragma unroll
    for (int z = 0; z < 3; ++z)
#pragma unroll
        for (int i = 0; i < 4; ++i)
#pragma unroll
            for (int j = 0; j < 2; ++j) acc[z][i][j] = (f32x4){0.f, 0.f, 0.f, 0.f};

    bf16x8 af[4], wf[3][2];
#pragma unroll
    for (int i = 0; i < 4; ++i) af[i] = *(const bf16x8*)(ap + i * 12288);
#pragma unroll
    for (int j = 0; j < 2; ++j) {
        wf[0][j] = *(const bf16x8*)(wqp + j * 12288);
        wf[1][j] = *(const bf16x8*)(wkp + j * 12288);
        wf[2][j] = *(const bf16x8*)(wvp + j * 12288);
    }

    for (int kb = 0; kb < 24; ++kb) {
#pragma unroll
        for (int z = 0; z < 3; ++z)
#pragma unroll
            for (int i = 0; i < 4; ++i)
#pragma unroll
                for (int j = 0; j < 2; ++j)
                    acc[z][i][j] = __builtin_amdgcn_mfma_f32_16x16x32_bf16(
                        af[i], wf[z][j], acc[z][i][j], 0, 0, 0);
        const int kn = (kb < 23) ? kb + 1 : 23;
#pragma unroll
        for (int i = 0; i < 4; ++i)
            af[i] = *(const bf16x8*)(ap + i * 12288 + kn * 512);
#pragma unroll
        for (int j = 0; j < 2; ++j) {
            wf[0][j] = *(const bf16x8*)(wqp + j * 12288 + kn * 512);
            wf[1][j] = *(const bf16x8*)(wkp + j * 12288 + kn * 512);
            wf[2][j] = *(const bf16x8*)(wvp + j * 12288 + kn * 512);
        }
    }

    // ---------------- epilogues (per-wave private strips, no syncs) -------
    const int b  = m0 >> 10, nb = m0 & 1023;
    const int hcol = n0 + wv * 32;
    const int h = hcol >> 6, uh = (hcol >> 5) & 1;
    const int bh = b * 12 + h;
    ushort_t* scr = smem + wv * 2304;

    float bias2[3][2];
#pragma unroll
    for (int j = 0; j < 2; ++j) {
        bias2[0][j] = bq[hcol + j * 16 + c];
        bias2[1][j] = bk[hcol + j * 16 + c];
        bias2[2][j] = bv[hcol + j * 16 + c];
    }

    // z=0: Q plain [bh][token][hd64]; token-major strip [64][36]
#pragma unroll
    for (int i = 0; i < 4; ++i)
#pragma unroll
        for (int j = 0; j < 2; ++j)
#pragma unroll
            for (int r = 0; r < 4; ++r)
                scr[(i * 16 + g * 4 + r) * 36 + j * 16 + c] =
                    f2bf(acc[0][i][j][r] + bias2[0][j]);
#pragma unroll
    for (int e = 0; e < 4; ++e) {
        const int slot = e * 64 + L;
        const int row = slot >> 2, ch = slot & 3;
        const u32x4 v = *(const u32x4*)&scr[row * 36 + ch * 8];
        *(u32x4*)&Qh[((size_t)bh * 1024 + nb + row) * 64 + uh * 32 + ch * 8] = v;
    }

    // z=1: K frag-linear; token-major strip again
#pragma unroll
    for (int i = 0; i < 4; ++i)
#pragma unroll
        for (int j = 0; j < 2; ++j)
#pragma unroll
            for (int r = 0; r < 4; ++r)
                scr[(i * 16 + g * 4 + r) * 36 + j * 16 + c] =
                    f2bf(acc[1][i][j][r] + bias2[1][j]);
#pragma unroll
    for (int tau = 0; tau < 4; ++tau) {
        const u32x4 v = *(const u32x4*)&scr[(tau * 16 + c) * 36 + g * 8];
        *(u32x4*)&Kl[(((size_t)bh * 64 + (nb >> 4) + tau) * 2 + uh) * 512
                     + (size_t)L * 8] = v;
    }

    // z=2: V frag-linear; hd-major strip [32][68]
#pragma unroll
    for (int i = 0; i < 4; ++i)
#pragma unroll
        for (int j = 0; j < 2; ++j)
#pragma unroll
            for (int r = 0; r < 4; ++r)
                scr[(j * 16 + c) * 68 + i * 16 + g * 4 + r] =
                    f2bf(acc[2][i][j][r] + bias2[2][j]);
    const int T = nb >> 6;
#pragma unroll
    for (int t = 0; t < 4; ++t) {
        const int htl = t >> 1, u = t & 1;
        const u32x4 v = *(const u32x4*)&scr[(htl * 16 + c) * 68 + u * 32 + g * 8];
        *(u32x4*)&Vl[((((size_t)bh * 4 + uh * 2 + htl) * 16 + T) * 2 + u) * 512
                     + (size_t)L * 8] = v;
    }
}

// ---------------------------------------------------------------------------
// Out-proj GEMM, LDS-free/barrier-free (R20 shape): 64m x 128n block,
// 4 waves. 1D grid 768, XCD-chunked like qkv.
// ---------------------------------------------------------------------------
__global__ __launch_bounds__(256, 3)
void gemm_outp(const ushort_t* __restrict__ attnb, const ushort_t* __restrict__ wob,
               const float* __restrict__ bo, float* __restrict__ out)
{
    const int tid = threadIdx.x, L = tid & 63, wv = tid >> 6;
    const int c = L & 15, g = L >> 4;
    const int bid = blockIdx.x;
    const int xcd = bid & 7, idx = bid >> 3;
    const int by = xcd * 16 + idx / 6, bx = idx % 6;
    const int n0 = bx * 128, m0 = by * 64;

    const ushort_t* ap = attnb + (size_t)(by * 4) * 24 * 512 + (size_t)L * 8;
    const size_t wbase = ((size_t)(bx * 8 + wv * 2) * 24 * 64 + L) * 8;
    const ushort_t* wop = wob + wbase;

    f32x4 acc[4][2];
#pragma unroll
    for (int i = 0; i < 4; ++i)
#pragma unroll
        for (int j = 0; j < 2; ++j) acc[i][j] = (f32x4){0.f, 0.f, 0.f, 0.f};

    bf16x8 af[4], wf[2];
#pragma unroll
    for (int i = 0; i < 4; ++i) af[i] = *(const bf16x8*)(ap + i * 12288);
#pragma unroll
    for (int j = 0; j < 2; ++j) wf[j] = *(const bf16x8*)(wop + j * 12288);

    for (int kb = 0; kb < 24; ++kb) {
#pragma unroll
        for (int i = 0; i < 4; ++i)
#pragma unroll
            for (int j = 0; j < 2; ++j)
                acc[i][j] = __builtin_amdgcn_mfma_f32_16x16x32_bf16(
                    af[i], wf[j], acc[i][j], 0, 0, 0);
        const int kn = (kb < 23) ? kb + 1 : 23;
#pragma unroll
        for (int i = 0; i < 4; ++i)
            af[i] = *(const bf16x8*)(ap + i * 12288 + kn * 512);
#pragma unroll
        for (int j = 0; j < 2; ++j)
            wf[j] = *(const bf16x8*)(wop + j * 12288 + kn * 512);
    }

#pragma unroll
    for (int i = 0; i < 4; ++i) {
        const int row = m0 + i * 16 + g * 4;
#pragma unroll
        for (int j = 0; j < 2; ++j) {
            const int col = n0 + wv * 32 + j * 16 + c;
            const float bsvo = bo[col];
#pragma unroll
            for (int r = 0; r < 4; ++r)
                out[(size_t)(row + r) * 768 + col] = acc[i][j][r] + bsvo;
        }
    }
}

// ---------------------------------------------------------------------------
// Flash (R12 body + XCD swizzle; frag-linear attnb epilogue): S^T =
// K.Q^T, fixed-max softmax, 1 wave/block, 32 q-rows, parity P-strips,
// in-place K prefetch, bare v_exp_f32. 1D grid 3072: xcd = bid&7 owns
// 12 complete bh. Do NOT tighten launch bounds / insert setprio /
// re-split waves (spills or intensity loss: R13/R14/R16/R23/R24).
// ---------------------------------------------------------------------------
__global__ __launch_bounds__(64, 3)
void flash_bf16(const ushort_t* __restrict__ Q, const ushort_t* __restrict__ Kl,
                const ushort_t* __restrict__ Vl, ushort_t* __restrict__ attnb)
{
    __shared__ ushort_t Ps[2][2][16 * 68];     // [parity][qgroup]
    const int L = threadIdx.x;                 // 0..63
    const int c = L & 15, g = L >> 4;
    const int bid = blockIdx.x;
    const int slot = bid >> 3;                 // 0..383 within XCD
    const int bh = (bid & 7) * 12 + (slot >> 5);
    const int q0 = (slot & 31) * 32;
    const float SC2 = 0.05205954985329743f;    // 768^-0.5 * log2(e)

    const ushort_t* Qp = Q + ((size_t)bh * 1024 + q0 + c) * 64 + g * 8;
    bf16x8 qf[2][2];
    qf[0][0] = *(const bf16x8*)Qp;
    qf[0][1] = *(const bf16x8*)(Qp + 32);
    qf[1][0] = *(const bf16x8*)(Qp + 16 * 64);
    qf[1][1] = *(const bf16x8*)(Qp + 16 * 64 + 32);

    const ushort_t* Kb = Kl + (size_t)bh * 65536 + (size_t)L * 8;
    const ushort_t* Vb = Vl + (size_t)bh * 65536 + (size_t)L * 8;

    f32x4 o[2][4];
#pragma unroll
    for (int w = 0; w < 2; ++w)
#pragma unroll
        for (int ht = 0; ht < 4; ++ht) o[w][ht] = (f32x4){0.f, 0.f, 0.f, 0.f};
    float ls[2] = {0.f, 0.f};

    bf16x8 kf0[4], kf1[4];
#pragma unroll
    for (int ct = 0; ct < 4; ++ct) {
        kf0[ct] = *(const bf16x8*)(Kb + (size_t)(ct * 2 + 0) * 512);
        kf1[ct] = *(const bf16x8*)(Kb + (size_t)(ct * 2 + 1) * 512);
    }

    for (int T0 = 0; T0 < 16; T0 += 2) {
#pragma unroll
        for (int p = 0; p < 2; ++p) {
            const int T = T0 + p;
            bf16x8 vf0[4], vf1[4];
#pragma unroll
            for (int ht = 0; ht < 4; ++ht) {
                const ushort_t* vp = Vb + (size_t)((ht * 16 + T) * 2) * 512;
                vf0[ht] = *(const bf16x8*)vp;
                vf1[ht] = *(const bf16x8*)(vp + 512);
            }
            f32x4 s[2][4];
#pragma unroll
            for (int w = 0; w < 2; ++w)
#pragma unroll
                for (int ct = 0; ct < 4; ++ct) {
                    f32x4 zz = (f32x4){0.f, 0.f, 0.f, 0.f};
                    zz = __builtin_amdgcn_mfma_f32_16x16x32_bf16(kf0[ct], qf[w][0], zz, 0, 0, 0);
                    zz = __builtin_amdgcn_mfma_f32_16x16x32_bf16(kf1[ct], qf[w][1], zz, 0, 0, 0);
                    s[w][ct] = zz;
                }
            const int Tn = (T < 15) ? T + 1 : 15;
#pragma unroll
            for (int ct = 0; ct < 4; ++ct) {
                const ushort_t* kp = Kb + (size_t)((Tn * 4 + ct) * 2) * 512;
                kf0[ct] = *(const bf16x8*)kp;
                kf1[ct] = *(const bf16x8*)(kp + 512);
            }
#pragma unroll
            for (int w = 0; w < 2; ++w) {
#pragma unroll
                for (int ct = 0; ct < 4; ++ct) {
                    float pv[4];
#pragma unroll
                    for (int r = 0; r < 4; ++r)
                        pv[r] = __builtin_amdgcn_exp2f(s[w][ct][r] * SC2);
                    ls[w] += (pv[0] + pv[1]) + (pv[2] + pv[3]);
                    const unsigned w01 = __builtin_amdgcn_perm(
                        __float_as_uint(pv[1]), __float_as_uint(pv[0]), 0x07060302u);
                    const unsigned w23 = __builtin_amdgcn_perm(
                        __float_as_uint(pv[3]), __float_as_uint(pv[2]), 0x07060302u);
                    *(u32x2*)&Ps[p][w][c * 68 + ct * 16 + g * 4] = (u32x2){w01, w23};
                }
            }
#pragma unroll
            for (int w = 0; w < 2; ++w) {
                const int pb = c * 68 + g * 8;
                const u32x4 pa  = *(const u32x4*)&Ps[p][w][pb];
                const u32x4 pbv = *(const u32x4*)&Ps[p][w][pb + 32];
                const bf16x8 pf0 = __builtin_bit_cast(bf16x8, pa);
                const bf16x8 pf1 = __builtin_bit_cast(bf16x8, pbv);
#pragma unroll
                for (int ht = 0; ht < 4; ++ht) {
                    o[w][ht] = __builtin_amdgcn_mfma_f32_16x16x32_bf16(vf0[ht], pf0, o[w][ht], 0, 0, 0);
                    o[w][ht] = __builtin_amdgcn_mfma_f32_16x16x32_bf16(vf1[ht], pf1, o[w][ht], 0, 0, 0);
                }
            }
        }
    }

    const int b = bh / 12, h = bh % 12;
    const int tB = b * 64 + (q0 >> 4);         // token-tile base (w adds +w)
#pragma unroll
    for (int w = 0; w < 2; ++w) {
        float l = ls[w];
        l += __shfl_xor(l, 16);
        l += __shfl_xor(l, 32);
        const float inv = 1.f / l;
#pragma unroll
        for (int ht = 0; ht < 4; ++ht) {
            const unsigned w0 = pk16(f2bf(o[w][ht][0] * inv), f2bf(o[w][ht][1] * inv));
            const unsigned w1 = pk16(f2bf(o[w][ht][2] * inv), f2bf(o[w][ht][3] * inv));
            *(u32x2*)&Ps[0][w][c * 68 + ht * 16 + g * 4] = (u32x2){w0, w1};
        }
        // frag-linear store: tile t = tB + w, kb = h*2 + kbi; lane L holds
        // row c, hd kbi*32 + g*8..+7 (read from [qrow][hd] strip).
#pragma unroll
        for (int kbi = 0; kbi < 2; ++kbi) {
            const u32x4 v = *(const u32x4*)&Ps[0][w][c * 68 + kbi * 32 + g * 8];
            *(u32x4*)&attnb[(((size_t)(tB + w) * 24 + h * 2 + kbi) * 64 + L) * 8] = v;
        }
    }
}

extern "C" void kernel_launch(void* const* d_in, const int* in_sizes, int n_in,
                              void* d_out, int out_size, void* d_ws, size_t ws_size,
                              hipStream_t stream)
{
    const float* x  = (const float*)d_in[0];
    const float* Wq = (const float*)d_in[1];
    const float* bq = (const float*)d_in[2];
    const float* Wk = (const float*)d_in[3];
    const float* bk = (const float*)d_in[4];
    const float* Wv = (const float*)d_in[5];
    const float* bv = (const float*)d_in[6];
    const float* Wo = (const float*)d_in[7];
    const float* bo = (const float*)d_in[8];
    float* out = (float*)d_out;

    char* ws = (char*)d_ws;
    ushort_t* xb    = (ushort_t*)(ws);
    ushort_t* wqb   = (ushort_t*)(ws + 12582912);
    ushort_t* wkb   = (ushort_t*)(ws + 12582912 + 1179648);
    ushort_t* wvb   = (ushort_t*)(ws + 12582912 + 2359296);
    ushort_t* wob   = (ushort_t*)(ws + 12582912 + 3538944);
    ushort_t* Qh    = (ushort_t*)(ws + 17301504);
    ushort_t* Kl    = (ushort_t*)(ws + 29884416);
    ushort_t* Vl    = (ushort_t*)(ws + 42467328);
    ushort_t* attnb = (ushort_t*)(ws + 55050240);

    cast_all<<<dim3(4224), 256, 0, stream>>>(x, Wq, Wk, Wv, Wo,
                                             xb, wqb, wkb, wvb, wob);
    gemm_qkv<<<dim3(768), 256, 0, stream>>>(xb, wqb, wkb, wvb,
                                            bq, bk, bv, Qh, Kl, Vl);
    flash_bf16<<<dim3(3072), 64, 0, stream>>>(Qh, Kl, Vl, attnb);
    gemm_outp<<<dim3(768), 256, 0, stream>>>(attnb, wob, bo, out);
}

// Round 14
// 178.375 us; speedup vs baseline: 1.2710x; 1.0151x over previous
//
#include <hip/hip_runtime.h>
#include <math.h>

// Round 26: fold the softmax scale SC2 = 768^-0.5*log2(e) into Q at the
// gemm_qkv epilogue (one f32 mul per Q element, once) and drop the
// per-element v_mul in flash's exp path (was 32 muls x 16 iters per
// wave, ~10% of flash's VALU chain). Flash is VALU-chain-bound at the
// unique feasible point of the register/intensity/occupancy triangle
// (R13/14/16/23/24 ledger); this is the last zero-structural-risk
// lever. Everything else byte-identical to R25/R22 (180-181us best).

typedef __bf16 bf16x8 __attribute__((ext_vector_type(8)));
typedef float  f32x4  __attribute__((ext_vector_type(4)));
typedef unsigned u32x2 __attribute__((ext_vector_type(2)));
typedef unsigned u32x4 __attribute__((ext_vector_type(4)));
typedef unsigned short ushort_t;

__device__ __forceinline__ unsigned short f2bf(float f) {
    unsigned u = __float_as_uint(f);
    u += 0x7fffu + ((u >> 16) & 1u);          // round-to-nearest-even
    return (unsigned short)(u >> 16);
}
__device__ __forceinline__ unsigned pk16(unsigned short lo, unsigned short hi) {
    return (unsigned)lo | ((unsigned)hi << 16);
}

// ---------------------------------------------------------------------------
// cast (1D grid, 4224 blocks, 4 tiles/block): everything frag-linear.
// Tile (t,kb) of source S holds S[t*16+c][kb*32+g*8..+7] at
// ((t*24+kb)*64 + L)*8. Tiles 0..12287 = x->xb; then 4x1152 for weights.
// ---------------------------------------------------------------------------
__global__ __launch_bounds__(256)
void cast_all(const float* __restrict__ x,
              const float* __restrict__ w0, const float* __restrict__ w1,
              const float* __restrict__ w2, const float* __restrict__ w3,
              ushort_t* __restrict__ xb, ushort_t* __restrict__ wb0,
              ushort_t* __restrict__ wb1, ushort_t* __restrict__ wb2,
              ushort_t* __restrict__ wb3)
{
    const int wt0 = blockIdx.x * 4 + (threadIdx.x >> 6);
    const int L = threadIdx.x & 63, c = L & 15, g = L >> 4;
    const float* s; ushort_t* d; int tile;
    if (wt0 < 12288) {                 // x: 512 t-tiles x 24 kb
        s = x; d = xb; tile = wt0;
    } else {
        const int wt = wt0 - 12288;    // weights: 48 t-tiles x 24 kb each
        const int wsel = wt / 1152; tile = wt % 1152;
        switch (wsel) {
            case 0:  s = w0; d = wb0; break;
            case 1:  s = w1; d = wb1; break;
            case 2:  s = w2; d = wb2; break;
            default: s = w3; d = wb3; break;
        }
    }
    const int t = tile / 24, kb = tile % 24;
    const float* sp = s + (size_t)(t * 16 + c) * 768 + kb * 32 + g * 8;
    const float4 f0 = *(const float4*)sp;
    const float4 f1 = *(const float4*)(sp + 4);
    ushort4 p0, p1;
    p0.x = f2bf(f0.x); p0.y = f2bf(f0.y); p0.z = f2bf(f0.z); p0.w = f2bf(f0.w);
    p1.x = f2bf(f1.x); p1.y = f2bf(f1.y); p1.z = f2bf(f1.z); p1.w = f2bf(f1.w);
    ushort_t* dp = d + ((size_t)tile * 64 + L) * 8;
    *(ushort4*)dp       = p0;
    *(ushort4*)(dp + 4) = p1;
}

// ---------------------------------------------------------------------------
// Z-fused QKV GEMM, barrier-free (R20 shape): 64m x 128n block, 4 waves
// (each 64m x 32n x 3z). A and W frags direct from frag-linear global
// with in-place prefetch. 1D grid 768, XCD-chunked: xcd owns a by-range.
// Q epilogue pre-scales by SC2 (softmax scale folded out of flash).
// ---------------------------------------------------------------------------
__global__ __launch_bounds__(256, 3)
void gemm_qkv(const ushort_t* __restrict__ xb,
              const ushort_t* __restrict__ wqb, const ushort_t* __restrict__ wkb,
              const ushort_t* __restrict__ wvb,
              const float* __restrict__ bq, const float* __restrict__ bk,
              const float* __restrict__ bv,
              ushort_t* __restrict__ Qh, ushort_t* __restrict__ Kl,
              ushort_t* __restrict__ Vl)
{
    __shared__ ushort_t smem[9216];      // epilogue scratch 4x2304, per-wave
    const int tid = threadIdx.x, L = tid & 63, wv = tid >> 6;
    const int c = L & 15, g = L >> 4;
    // XCD A-locality: xcd = bid&7 handles by in [xcd*16, xcd*16+16), all bx.
    const int bid = blockIdx.x;
    const int xcd = bid & 7, idx = bid >> 3;       // idx 0..95
    const int by = xcd * 16 + idx / 6, bx = idx % 6;
    const int n0 = bx * 128, m0 = by * 64;
    const float SC2 = 0.05205954985329743f;        // 768^-0.5 * log2(e)

    // A frag tiles t = by*4 + i; af[i] at ap + i*12288 + kb*512
    const ushort_t* ap = xb + (size_t)(by * 4) * 24 * 512 + (size_t)L * 8;
    // W frag tiles t = bx*8 + wv*2 + j
    const size_t wbase = ((size_t)(bx * 8 + wv * 2) * 24 * 64 + L) * 8;
    const ushort_t* wqp = wqb + wbase;
    const ushort_t* wkp = wkb + wbase;
    const ushort_t* wvp = wvb + wbase;
    // j/i tile stride = 24*64*8 = 12288 shorts; kb stride = 512 shorts

    f32x4 acc[3][4][2];
#pragma unroll
    for (int z = 0; z < 3; ++z)
#pragma unroll
        for (int i = 0; i < 4; ++i)
#pragma unroll
            for (int j = 0; j < 2; ++j) acc[z][i][j] = (f32x4){0.f, 0.f, 0.f, 0.f};

    bf16x8 af[4], wf[3][2];
#pragma unroll
    for (int i = 0; i < 4; ++i) af[i] = *(const bf16x8*)(ap + i * 12288);
#pragma unroll
    for (int j = 0; j < 2; ++j) {
        wf[0][j] = *(const bf16x8*)(wqp + j * 12288);
        wf[1][j] = *(const bf16x8*)(wkp + j * 12288);
        wf[2][j] = *(const bf16x8*)(wvp + j * 12288);
    }

    for (int kb = 0; kb < 24; ++kb) {
#pragma unroll
        for (int z = 0; z < 3; ++z)
#pragma unroll
            for (int i = 0; i < 4; ++i)
#pragma unroll
                for (int j = 0; j < 2; ++j)
                    acc[z][i][j] = __builtin_amdgcn_mfma_f32_16x16x32_bf16(
                        af[i], wf[z][j], acc[z][i][j], 0, 0, 0);
        const int kn = (kb < 23) ? kb + 1 : 23;
#pragma unroll
        for (int i = 0; i < 4; ++i)
            af[i] = *(const bf16x8*)(ap + i * 12288 + kn * 512);
#pragma unroll
        for (int j = 0; j < 2; ++j) {
            wf[0][j] = *(const bf16x8*)(wqp + j * 12288 + kn * 512);
            wf[1][j] = *(const bf16x8*)(wkp + j * 12288 + kn * 512);
            wf[2][j] = *(const bf16x8*)(wvp + j * 12288 + kn * 512);
        }
    }

    // ---------------- epilogues (per-wave private strips, no syncs) -------
    const int b  = m0 >> 10, nb = m0 & 1023;
    const int hcol = n0 + wv * 32;
    const int h = hcol >> 6, uh = (hcol >> 5) & 1;
    const int bh = b * 12 + h;
    ushort_t* scr = smem + wv * 2304;

    float bias2[3][2];
#pragma unroll
    for (int j = 0; j < 2; ++j) {
        bias2[0][j] = bq[hcol + j * 16 + c];
        bias2[1][j] = bk[hcol + j * 16 + c];
        bias2[2][j] = bv[hcol + j * 16 + c];
    }

    // z=0: Q plain [bh][token][hd64], PRE-SCALED by SC2; strip [64][36]
#pragma unroll
    for (int i = 0; i < 4; ++i)
#pragma unroll
        for (int j = 0; j < 2; ++j)
#pragma unroll
            for (int r = 0; r < 4; ++r)
                scr[(i * 16 + g * 4 + r) * 36 + j * 16 + c] =
                    f2bf((acc[0][i][j][r] + bias2[0][j]) * SC2);
#pragma unroll
    for (int e = 0; e < 4; ++e) {
        const int slot = e * 64 + L;
        const int row = slot >> 2, ch = slot & 3;
        const u32x4 v = *(const u32x4*)&scr[row * 36 + ch * 8];
        *(u32x4*)&Qh[((size_t)bh * 1024 + nb + row) * 64 + uh * 32 + ch * 8] = v;
    }

    // z=1: K frag-linear; token-major strip again
#pragma unroll
    for (int i = 0; i < 4; ++i)
#pragma unroll
        for (int j = 0; j < 2; ++j)
#pragma unroll
            for (int r = 0; r < 4; ++r)
                scr[(i * 16 + g * 4 + r) * 36 + j * 16 + c] =
                    f2bf(acc[1][i][j][r] + bias2[1][j]);
#pragma unroll
    for (int tau = 0; tau < 4; ++tau) {
        const u32x4 v = *(const u32x4*)&scr[(tau * 16 + c) * 36 + g * 8];
        *(u32x4*)&Kl[(((size_t)bh * 64 + (nb >> 4) + tau) * 2 + uh) * 512
                     + (size_t)L * 8] = v;
    }

    // z=2: V frag-linear; hd-major strip [32][68]
#pragma unroll
    for (int i = 0; i < 4; ++i)
#pragma unroll
        for (int j = 0; j < 2; ++j)
#pragma unroll
            for (int r = 0; r < 4; ++r)
                scr[(j * 16 + c) * 68 + i * 16 + g * 4 + r] =
                    f2bf(acc[2][i][j][r] + bias2[2][j]);
    const int T = nb >> 6;
#pragma unroll
    for (int t = 0; t < 4; ++t) {
        const int htl = t >> 1, u = t & 1;
        const u32x4 v = *(const u32x4*)&scr[(htl * 16 + c) * 68 + u * 32 + g * 8];
        *(u32x4*)&Vl[((((size_t)bh * 4 + uh * 2 + htl) * 16 + T) * 2 + u) * 512
                     + (size_t)L * 8] = v;
    }
}

// ---------------------------------------------------------------------------
// Out-proj GEMM, LDS-free/barrier-free (R20 shape): 64m x 128n block,
// 4 waves. 1D grid 768, XCD-chunked like qkv.
// ---------------------------------------------------------------------------
__global__ __launch_bounds__(256, 3)
void gemm_outp(const ushort_t* __restrict__ attnb, const ushort_t* __restrict__ wob,
               const float* __restrict__ bo, float* __restrict__ out)
{
    const int tid = threadIdx.x, L = tid & 63, wv = tid >> 6;
    const int c = L & 15, g = L >> 4;
    const int bid = blockIdx.x;
    const int xcd = bid & 7, idx = bid >> 3;
    const int by = xcd * 16 + idx / 6, bx = idx % 6;
    const int n0 = bx * 128, m0 = by * 64;

    const ushort_t* ap = attnb + (size_t)(by * 4) * 24 * 512 + (size_t)L * 8;
    const size_t wbase = ((size_t)(bx * 8 + wv * 2) * 24 * 64 + L) * 8;
    const ushort_t* wop = wob + wbase;

    f32x4 acc[4][2];
#pragma unroll
    for (int i = 0; i < 4; ++i)
#pragma unroll
        for (int j = 0; j < 2; ++j) acc[i][j] = (f32x4){0.f, 0.f, 0.f, 0.f};

    bf16x8 af[4], wf[2];
#pragma unroll
    for (int i = 0; i < 4; ++i) af[i] = *(const bf16x8*)(ap + i * 12288);
#pragma unroll
    for (int j = 0; j < 2; ++j) wf[j] = *(const bf16x8*)(wop + j * 12288);

    for (int kb = 0; kb < 24; ++kb) {
#pragma unroll
        for (int i = 0; i < 4; ++i)
#pragma unroll
            for (int j = 0; j < 2; ++j)
                acc[i][j] = __builtin_amdgcn_mfma_f32_16x16x32_bf16(
                    af[i], wf[j], acc[i][j], 0, 0, 0);
        const int kn = (kb < 23) ? kb + 1 : 23;
#pragma unroll
        for (int i = 0; i < 4; ++i)
            af[i] = *(const bf16x8*)(ap + i * 12288 + kn * 512);
#pragma unroll
        for (int j = 0; j < 2; ++j)
            wf[j] = *(const bf16x8*)(wop + j * 12288 + kn * 512);
    }

#pragma unroll
    for (int i = 0; i < 4; ++i) {
        const int row = m0 + i * 16 + g * 4;
#pragma unroll
        for (int j = 0; j < 2; ++j) {
            const int col = n0 + wv * 32 + j * 16 + c;
            const float bsvo = bo[col];
#pragma unroll
            for (int r = 0; r < 4; ++r)
                out[(size_t)(row + r) * 768 + col] = acc[i][j][r] + bsvo;
        }
    }
}

// ---------------------------------------------------------------------------
// Flash (R12 body + XCD swizzle; frag-linear attnb epilogue): S^T =
// K.Q^T with Q PRE-SCALED by SC2 (exp2 applied directly to s), fixed-max
// softmax, 1 wave/block, 32 q-rows, parity P-strips, in-place K
// prefetch. 1D grid 3072: xcd = bid&7 owns 12 complete bh. Do NOT
// tighten launch bounds / insert setprio / re-split waves (spills or
// intensity loss: R13/R14/R16/R23/R24).
// ---------------------------------------------------------------------------
__global__ __launch_bounds__(64, 3)
void flash_bf16(const ushort_t* __restrict__ Q, const ushort_t* __restrict__ Kl,
                const ushort_t* __restrict__ Vl, ushort_t* __restrict__ attnb)
{
    __shared__ ushort_t Ps[2][2][16 * 68];     // [parity][qgroup]
    const int L = threadIdx.x;                 // 0..63
    const int c = L & 15, g = L >> 4;
    const int bid = blockIdx.x;
    const int slot = bid >> 3;                 // 0..383 within XCD
    const int bh = (bid & 7) * 12 + (slot >> 5);
    const int q0 = (slot & 31) * 32;

    const ushort_t* Qp = Q + ((size_t)bh * 1024 + q0 + c) * 64 + g * 8;
    bf16x8 qf[2][2];
    qf[0][0] = *(const bf16x8*)Qp;
    qf[0][1] = *(const bf16x8*)(Qp + 32);
    qf[1][0] = *(const bf16x8*)(Qp + 16 * 64);
    qf[1][1] = *(const bf16x8*)(Qp + 16 * 64 + 32);

    const ushort_t* Kb = Kl + (size_t)bh * 65536 + (size_t)L * 8;
    const ushort_t* Vb = Vl + (size_t)bh * 65536 + (size_t)L * 8;

    f32x4 o[2][4];
#pragma unroll
    for (int w = 0; w < 2; ++w)
#pragma unroll
        for (int ht = 0; ht < 4; ++ht) o[w][ht] = (f32x4){0.f, 0.f, 0.f, 0.f};
    float ls[2] = {0.f, 0.f};

    bf16x8 kf0[4], kf1[4];
#pragma unroll
    for (int ct = 0; ct < 4; ++ct) {
        kf0[ct] = *(const bf16x8*)(Kb + (size_t)(ct * 2 + 0) * 512);
        kf1[ct] = *(const bf16x8*)(Kb + (size_t)(ct * 2 + 1) * 512);
    }

    for (int T0 = 0; T0 < 16; T0 += 2) {
#pragma unroll
        for (int p = 0; p < 2; ++p) {
            const int T = T0 + p;
            bf16x8 vf0[4], vf1[4];
#pragma unroll
            for (int ht = 0; ht < 4; ++ht) {
                const ushort_t* vp = Vb + (size_t)((ht * 16 + T) * 2) * 512;
                vf0[ht] = *(const bf16x8*)vp;
                vf1[ht] = *(const bf16x8*)(vp + 512);
            }
            f32x4 s[2][4];
#pragma unroll
            for (int w = 0; w < 2; ++w)
#pragma unroll
                for (int ct = 0; ct < 4; ++ct) {
                    f32x4 zz = (f32x4){0.f, 0.f, 0.f, 0.f};
                    zz = __builtin_amdgcn_mfma_f32_16x16x32_bf16(kf0[ct], qf[w][0], zz, 0, 0, 0);
                    zz = __builtin_amdgcn_mfma_f32_16x16x32_bf16(kf1[ct], qf[w][1], zz, 0, 0, 0);
                    s[w][ct] = zz;
                }
            const int Tn = (T < 15) ? T + 1 : 15;
#pragma unroll
            for (int ct = 0; ct < 4; ++ct) {
                const ushort_t* kp = Kb + (size_t)((Tn * 4 + ct) * 2) * 512;
                kf0[ct] = *(const bf16x8*)kp;
                kf1[ct] = *(const bf16x8*)(kp + 512);
            }
#pragma unroll
            for (int w = 0; w < 2; ++w) {
#pragma unroll
                for (int ct = 0; ct < 4; ++ct) {
                    float pv[4];
#pragma unroll
                    for (int r = 0; r < 4; ++r)
                        pv[r] = __builtin_amdgcn_exp2f(s[w][ct][r]);
                    ls[w] += (pv[0] + pv[1]) + (pv[2] + pv[3]);
                    const unsigned w01 = __builtin_amdgcn_perm(
                        __float_as_uint(pv[1]), __float_as_uint(pv[0]), 0x07060302u);
                    const unsigned w23 = __builtin_amdgcn_perm(
                        __float_as_uint(pv[3]), __float_as_uint(pv[2]), 0x07060302u);
                    *(u32x2*)&Ps[p][w][c * 68 + ct * 16 + g * 4] = (u32x2){w01, w23};
                }
            }
#pragma unroll
            for (int w = 0; w < 2; ++w) {
                const int pb = c * 68 + g * 8;
                const u32x4 pa  = *(const u32x4*)&Ps[p][w][pb];
                const u32x4 pbv = *(const u32x4*)&Ps[p][w][pb + 32];
                const bf16x8 pf0 = __builtin_bit_cast(bf16x8, pa);
                const bf16x8 pf1 = __builtin_bit_cast(bf16x8, pbv);
#pragma unroll
                for (int ht = 0; ht < 4; ++ht) {
                    o[w][ht] = __builtin_amdgcn_mfma_f32_16x16x32_bf16(vf0[ht], pf0, o[w][ht], 0, 0, 0);
                    o[w][ht] = __builtin_amdgcn_mfma_f32_16x16x32_bf16(vf1[ht], pf1, o[w][ht], 0, 0, 0);
                }
            }
        }
    }

    const int b = bh / 12, h = bh % 12;
    const int tB = b * 64 + (q0 >> 4);         // token-tile base (w adds +w)
#pragma unroll
    for (int w = 0; w < 2; ++w) {
        float l = ls[w];
        l += __shfl_xor(l, 16);
        l += __shfl_xor(l, 32);
        const float inv = 1.f / l;
#pragma unroll
        for (int ht = 0; ht < 4; ++ht) {
            const unsigned w0 = pk16(f2bf(o[w][ht][0] * inv), f2bf(o[w][ht][1] * inv));
            const unsigned w1 = pk16(f2bf(o[w][ht][2] * inv), f2bf(o[w][ht][3] * inv));
            *(u32x2*)&Ps[0][w][c * 68 + ht * 16 + g * 4] = (u32x2){w0, w1};
        }
        // frag-linear store: tile t = tB + w, kb = h*2 + kbi; lane L holds
        // row c, hd kbi*32 + g*8..+7 (read from [qrow][hd] strip).
#pragma unroll
        for (int kbi = 0; kbi < 2; ++kbi) {
            const u32x4 v = *(const u32x4*)&Ps[0][w][c * 68 + kbi * 32 + g * 8];
            *(u32x4*)&attnb[(((size_t)(tB + w) * 24 + h * 2 + kbi) * 64 + L) * 8] = v;
        }
    }
}

extern "C" void kernel_launch(void* const* d_in, const int* in_sizes, int n_in,
                              void* d_out, int out_size, void* d_ws, size_t ws_size,
                              hipStream_t stream)
{
    const float* x  = (const float*)d_in[0];
    const float* Wq = (const float*)d_in[1];
    const float* bq = (const float*)d_in[2];
    const float* Wk = (const float*)d_in[3];
    const float* bk = (const float*)d_in[4];
    const float* Wv = (const float*)d_in[5];
    const float* bv = (const float*)d_in[6];
    const float* Wo = (const float*)d_in[7];
    const float* bo = (const float*)d_in[8];
    float* out = (float*)d_out;

    char* ws = (char*)d_ws;
    ushort_t* xb    = (ushort_t*)(ws);
    ushort_t* wqb   = (ushort_t*)(ws + 12582912);
    ushort_t* wkb   = (ushort_t*)(ws + 12582912 + 1179648);
    ushort_t* wvb   = (ushort_t*)(ws + 12582912 + 2359296);
    ushort_t* wob   = (ushort_t*)(ws + 12582912 + 3538944);
    ushort_t* Qh    = (ushort_t*)(ws + 17301504);
    ushort_t* Kl    = (ushort_t*)(ws + 29884416);
    ushort_t* Vl    = (ushort_t*)(ws + 42467328);
    ushort_t* attnb = (ushort_t*)(ws + 55050240);

    cast_all<<<dim3(4224), 256, 0, stream>>>(x, Wq, Wk, Wv, Wo,
                                             xb, wqb, wkb, wvb, wob);
    gemm_qkv<<<dim3(768), 256, 0, stream>>>(xb, wqb, wkb, wvb,
                                            bq, bk, bv, Qh, Kl, Vl);
    flash_bf16<<<dim3(3072), 64, 0, stream>>>(Qh, Kl, Vl, attnb);
    gemm_outp<<<dim3(768), 256, 0, stream>>>(attnb, wob, bo, out);
}